// Round 4
// baseline (310.544 us; speedup 1.0000x reference)
//
#include <hip/hip_runtime.h>
#include <hip/hip_bf16.h>
#include <hip/hip_fp16.h>

#define BS 8
#define C  256
#define N  9216
#define E  9215
#define MAXD 128               // off[] bins; actual depth <= 64
#define NARROW 64              // level-size threshold for single-wave processing
#define NGT 31                 // weight tasks per batch (8 or 9 channels each)
#define NBLK 256               // 8 hybrid + 248 weight = 256 blocks = 256 CUs
                               // (1 block/CU @153KB LDS -> ALL resident: spin-wait deadlock-free)

typedef __attribute__((address_space(1))) const void GVoid;
typedef __attribute__((address_space(3))) void LVoid;

// ---------------------------------------------------------------------------
// Single fused kernel, perfectly load-balanced (R4).
//   blocks [0,8)     HYBRID: levels schedule (concurrent with weights) ->
//                    TSW.x scatter -> V init -> spin flagG[b]==31 ->
//                    TSW.y = exp(-zeta*dist) -> up pass (level-walk, 512thr)
//                    -> DOWN PASS VIA AFFINE POINTER-DOUBLING (6 rounds) -> out.
//   blocks [8,256)   WEIGHTS: (b, g) task, 9 ch for g<8 else 8 ch. Double-
//                    buffered global_load_lds staging; reg accumulation;
//                    atomicAdd distG; threadfence + agent release flag.
// Down-doubling: F[t] = a_t * F[p_t] + b_t with a=w, b=(1-w^2)*S[t]; root
// tuple (p=0, a=0, b=S[0]) is the fixed point. Compose 6x: covers depth 64.
// State: (p,a) overlays TSW (node-indexed), b overlays V. Jacobi rounds with
// register-held own-state and read/barrier/write/barrier discipline.
// ---------------------------------------------------------------------------
__global__ __launch_bounds__(1024) void fused_kernel(const float* __restrict__ feat,
                                                     const float* __restrict__ emb,
                                                     const int* __restrict__ tree,
                                                     float* __restrict__ distG,
                                                     int* __restrict__ flagG,
                                                     float* __restrict__ out) {
    __shared__ float2 V[N];           // hybrid: P|U overlay, then (F,G), then b-tuples
    __shared__ int2 TSW[N];           // edges (child|par<<16, w bits); then (p,a) tuples
    __shared__ int cnt8[MAXD * 8];
    __shared__ int tot[MAXD];
    __shared__ int sc1[MAXD];
    __shared__ int off[MAXD + 1];
    __shared__ int meta[3];           // maxd, loE, hiS
    __shared__ int maxd_sh;
    const int tid = threadIdx.x;

    if (blockIdx.x >= BS) {
        // ---- weights role ----
        const int wb = blockIdx.x - BS;       // [0,248)
        const int b  = wb & 7;                // batch fastest -> spreads XCD traffic
        const int g  = wb >> 3;               // [0,31)
        const int c0  = (g < 8) ? g * 9 : 72 + (g - 8) * 8;
        const int cpg = (g < 8) ? 9 : 8;
        const int wave = tid >> 6, lane = tid & 63;

        float* cur = (float*)V;               // two 36 KB halves of V
        float* nxt = (float*)V + N;

        int se[9];
        #pragma unroll
        for (int k = 0; k < 9; ++k) {
            int e = tid + k * 1024;
            se[k] = (e < E) ? tree[((size_t)b * E + e) * 2] : 0;
        }
        float acc[9];
        #pragma unroll
        for (int k = 0; k < 9; ++k) acc[k] = 0.f;

        // async stage: 36 KB row = 36 chunks of 1 KB (64 lanes x 16 B), 16 waves
        const float* rowbase = emb + ((size_t)b * C + c0) * N;
        for (int chk = wave; chk < 36; chk += 16)
            __builtin_amdgcn_global_load_lds(
                (GVoid*)(rowbase + chk * 256 + lane * 4),
                (LVoid*)(cur + chk * 256), 16, 0, 0);
        __syncthreads();                                 // ch0 ready

        for (int cc = 0; cc < cpg; ++cc) {
            if (cc + 1 < cpg) {                          // async prefetch next channel
                const float* src = rowbase + (size_t)(cc + 1) * N;
                for (int chk = wave; chk < 36; chk += 16)
                    __builtin_amdgcn_global_load_lds(
                        (GVoid*)(src + chk * 256 + lane * 4),
                        (LVoid*)(nxt + chk * 256), 16, 0, 0);
            }
            #pragma unroll
            for (int k = 0; k < 9; ++k) {
                int e = tid + k * 1024;
                if (e < E) {
                    float d = cur[se[k]] - cur[e + 1];   // tgt = e+1 (children=arange)
                    acc[k] += d * d;
                }
            }
            __syncthreads();                             // nxt staged + cur reads done
            float* t = cur; cur = nxt; nxt = t;
        }
        #pragma unroll
        for (int k = 0; k < 9; ++k) {
            int e = tid + k * 1024;
            if (e < E) atomicAdd(&distG[(size_t)b * N + e], acc[k]);
        }
        __syncthreads();                                 // all lanes' atomics drained
        __threadfence();                                 // release distG
        if (tid == 0)
            __hip_atomic_fetch_add(&flagG[b], 1, __ATOMIC_RELEASE,
                                   __HIP_MEMORY_SCOPE_AGENT);
        return;
    }

    // ---- hybrid role: levels + DP for batch b ----
    const int b = blockIdx.x;
    const int* tb = tree + b * E * 2;
    int* P = (int*)V;
    int* U = ((int*)V) + N;

    for (int t = tid; t < N; t += 1024)
        P[t] = (t == 0) ? 0 : (tb[(t - 1) * 2] | (1 << 16));
    for (int i = tid; i < MAXD * 8; i += 1024) cnt8[i] = 0;
    if (tid == 0) maxd_sh = 1;
    __syncthreads();

    for (int r = 0; r < 3; ++r) {                        // pointer doubling, depth<=64
        for (int t = tid; t < N; t += 1024) {
            int p = P[t];
            int a = p & 0xffff;
            if (a == 0) U[t] = p;
            else {
                int pa = P[a];
                U[t] = (pa & 0xffff) | (((p >> 16) + (pa >> 16)) << 16);
            }
        }
        __syncthreads();
        for (int t = tid; t < N; t += 1024) {
            int p = U[t];
            int a = p & 0xffff;
            if (a == 0) P[t] = p;
            else {
                int pa = U[a];
                P[t] = (pa & 0xffff) | (((p >> 16) + (pa >> 16)) << 16);
            }
        }
        __syncthreads();
    }

    for (int t = 1 + tid; t < N; t += 1024) {            // depth histogram
        int d = P[t] >> 16;
        atomicAdd(&cnt8[d * 8 + (tid >> 7)], 1);
    }
    __syncthreads();

    for (int d = tid; d < MAXD; d += 1024) {             // sub-prefix + totals
        int s = 0;
        #pragma unroll
        for (int k = 0; k < 8; ++k) {
            int v = cnt8[d * 8 + k];
            cnt8[d * 8 + k] = s;
            s += v;
        }
        tot[d] = s;
        if (s > 0) atomicMax(&maxd_sh, d);
    }
    __syncthreads();

    {                                                    // scan -> off
        int* src = tot; int* dst = sc1;
        for (int step = 1; step < MAXD; step <<= 1) {
            for (int d = tid; d < MAXD; d += 1024)
                dst[d] = src[d] + ((d >= step) ? src[d - step] : 0);
            __syncthreads();
            int* tmp = src; src = dst; dst = tmp;
        }
        for (int d = tid; d < MAXD; d += 1024) off[d + 1] = src[d];
        if (tid == 0) off[0] = 0;
    }
    __syncthreads();

    if (tid == 0) {                                      // narrow/wide markers
        int md = maxd_sh;
        int lo = 0;
        while (lo < md && off[lo + 2] - off[lo + 1] <= NARROW) ++lo;
        int hi = md + 1;
        while (hi > lo + 1 && off[hi] - off[hi - 1] <= NARROW) --hi;
        meta[0] = md; meta[1] = lo; meta[2] = hi;
    }
    for (int t = 1 + tid; t < N; t += 1024) {            // counting-sort scatter
        int d = P[t] >> 16;
        int idx = atomicAdd(&cnt8[d * 8 + (tid >> 7)], 1);
        int slot = off[d] + idx;
        int p = tb[(t - 1) * 2];
        TSW[slot].x = t | (p << 16);
    }
    __syncthreads();                                     // P/U dead

    for (int i = tid; i < N; i += 1024)                  // V init (overlaps weights)
        V[i] = make_float2(feat[b * N + i], 1.0f);

    if (tid == 0) {                                      // wait for 31 weight tasks
        while (__hip_atomic_load(&flagG[b], __ATOMIC_ACQUIRE,
                                 __HIP_MEMORY_SCOPE_AGENT) < NGT)
            __builtin_amdgcn_s_sleep(8);
    }
    __syncthreads();

    const float* dG = distG + b * N;                     // agent-scope coherent loads
    for (int i = tid; i < E; i += 1024) {
        int ts = TSW[i].x;
        float ds = __hip_atomic_load(&dG[(ts & 0xffff) - 1], __ATOMIC_RELAXED,
                                     __HIP_MEMORY_SCOPE_AGENT);
        TSW[i].y = __float_as_int(__expf(-0.01f * ds));
    }
    __syncthreads();
    const int maxd = meta[0], loE = meta[1], hiS = meta[2];

    // ---- up pass (level-walk; 512-thread sweet spot inside 1024 block) ----
    if (tid < 64) {                                      // narrow deep tail: wave 0
        for (int lev = maxd; lev >= hiS; --lev) {
            int s0 = off[lev], s1 = off[lev + 1];
            for (int i = s0 + tid; i < s1; i += 64) {
                int2 ew = TSW[i];
                int t = ew.x & 0xffff, p = ew.x >> 16;
                float w = __int_as_float(ew.y);
                float2 vt = V[t];
                atomicAdd(&V[p].x, w * vt.x);
                atomicAdd(&V[p].y, w * vt.y);
            }
            __threadfence_block();
        }
    }
    __syncthreads();
    for (int lev = hiS - 1; lev > loE; --lev) {          // wide middle
        int s0 = off[lev], s1 = off[lev + 1];
        if (tid < 512) {
            for (int i = s0 + tid; i < s1; i += 512) {
                int2 ew = TSW[i];
                int t = ew.x & 0xffff, p = ew.x >> 16;
                float w = __int_as_float(ew.y);
                float2 vt = V[t];
                atomicAdd(&V[p].x, w * vt.x);
                atomicAdd(&V[p].y, w * vt.y);
            }
        }
        __syncthreads();
    }
    if (tid < 64) {                                      // narrow top: wave 0
        for (int lev = loE; lev >= 1; --lev) {
            int s0 = off[lev], s1 = off[lev + 1];
            for (int i = s0 + tid; i < s1; i += 64) {
                int2 ew = TSW[i];
                int t = ew.x & 0xffff, p = ew.x >> 16;
                float w = __int_as_float(ew.y);
                float2 vt = V[t];
                atomicAdd(&V[p].x, w * vt.x);
                atomicAdd(&V[p].y, w * vt.y);
            }
            __threadfence_block();
        }
    }
    __syncthreads();                                     // V = S (post-up)

    // ---- down pass: affine pointer-doubling ----
    // Phase A: edge list -> node-indexed tuples. (p,a) -> TSW[t]; b -> V[t].
    int   own_t[9], own_p[9];
    float own_a[9];
    float2 own_b[9];
    int cnt = 0;
    for (int i = tid; i < E; i += 1024) {                // read edges to regs
        int2 ew = TSW[i];
        own_t[cnt] = ew.x & 0xffff;
        own_p[cnt] = ew.x >> 16;
        own_a[cnt] = __int_as_float(ew.y);
        ++cnt;
    }
    __syncthreads();                                     // all TSW reads done
    for (int k = 0; k < cnt; ++k) {                      // write node-indexed state
        int t = own_t[k];
        float w = own_a[k], c = 1.f - w * w;
        float2 s = V[t];
        float2 bb = make_float2(c * s.x, c * s.y);
        V[t] = bb;
        own_b[k] = bb;
        TSW[t] = make_int2(own_p[k], __float_as_int(w));
    }
    if (tid == 0) TSW[0] = make_int2(0, __float_as_int(0.f));  // root fixed point
    __syncthreads();

    for (int r = 0; r < 6; ++r) {                        // 2^6 = 64 >= maxd
        int   pp[9];
        float pa[9];
        float2 pb[9];
        for (int k = 0; k < cnt; ++k) {                  // read parents (state r)
            int p = own_p[k];
            int2 d = TSW[p];
            pp[k] = d.x;
            pa[k] = __int_as_float(d.y);
            pb[k] = V[p];
        }
        __syncthreads();
        for (int k = 0; k < cnt; ++k) {                  // compose + publish r+1
            float a = own_a[k];
            own_b[k].x = a * pb[k].x + own_b[k].x;
            own_b[k].y = a * pb[k].y + own_b[k].y;
            own_a[k] = a * pa[k];
            own_p[k] = pp[k];
            int t = own_t[k];
            TSW[t] = make_int2(own_p[k], __float_as_int(own_a[k]));
            V[t] = own_b[k];
        }
        __syncthreads();
    }
    // V[t] = final (F,G); root untouched (V[0]=S ✓)

    for (int i = tid; i < N; i += 1024) {
        float2 v = V[i];
        out[b * N + i] = v.x / v.y;
    }
}

extern "C" void kernel_launch(void* const* d_in, const int* in_sizes, int n_in,
                              void* d_out, int out_size, void* d_ws, size_t ws_size,
                              hipStream_t stream) {
    const float* feat = (const float*)d_in[0];   // [8,1,96,96]
    const float* emb  = (const float*)d_in[1];   // [8,256,96,96]
    const int*   tree = (const int*)d_in[2];     // [8,9215,2]
    float* out = (float*)d_out;                  // [8,1,96,96]

    const size_t BN = (size_t)BS * N;
    float* distG = (float*)d_ws;                             // BN f32
    int*   flagG = (int*)((char*)d_ws + BN * 4);             // BS i32

    hipMemsetAsync(d_ws, 0, BN * 4 + 256, stream);           // distG + flags
    fused_kernel<<<NBLK, 1024, 0, stream>>>(feat, emb, tree, distG, flagG, out);
}

// Round 5
// 160.492 us; speedup vs baseline: 1.9349x; 1.9349x over previous
//
#include <hip/hip_runtime.h>
#include <hip/hip_bf16.h>
#include <hip/hip_fp16.h>

#define BS 8
#define C  256
#define N  9216
#define E  9215
#define MAXD 128               // off[] bins; actual depth <= 64 (6 doubling iters)
#define LVL_STRIDE 192         // per-batch ints: [0..128]=off, 129=maxd, 130=loE, 131=hiS
#define NARROW 64              // level-size threshold for single-wave processing
#define NGT 31                 // weight tasks per batch: 8 tasks x 9ch + 23 x 8ch = 256
#define NBLK (BS + BS * NGT)   // 8 levels + 248 weights = 256 blocks = 256 CUs (1/CU)

typedef __attribute__((address_space(1))) const void GVoid;
typedef __attribute__((address_space(3))) void LVoid;

// ---------------------------------------------------------------------------
// Kernel 1: blocks [0,8) = per-batch level schedule; blocks [8,256) = weights.
// R5: R2 structure (two kernels, proven 167.9) + PERFECT LOAD BALANCE:
// R2 had 264 blocks on 256 CUs -> 8 CUs ran 2 weight blocks -> setup wall =
// 16 serial channels. Now 31 tasks/batch (9 or 8 ch), 256 blocks exactly,
// critical path = 9 serial channels. Double-buffered async global_load_lds
// staging (P/U overlays) unchanged; emb read once from HBM.
// ---------------------------------------------------------------------------
__global__ __launch_bounds__(1024) void setup_kernel(const float* __restrict__ emb,
                                                     const int* __restrict__ tree,
                                                     float* __restrict__ distG,
                                                     int* __restrict__ uparr,
                                                     int* __restrict__ lvlOff) {
    __shared__ int P[N];              // levels: anc|dep<<16 ; weights: row buf 0
    __shared__ int U[N];              // ping-pong partner; weights: row buf 1
    __shared__ int cnt8[MAXD * 8];    // 8 sub-counters per level
    __shared__ int tot[MAXD];
    __shared__ int sc1[MAXD];
    __shared__ int off[MAXD + 1];
    __shared__ int maxd_sh;
    const int tid = threadIdx.x;

    if (blockIdx.x >= BS) {
        // ---- weights role ----
        const int wb = blockIdx.x - BS;        // [0,248)
        const int b  = wb & 7;                 // batch fastest -> spreads XCD traffic
        const int g  = wb >> 3;                // [0,31)
        const int c0  = (g < 8) ? g * 9 : 72 + (g - 8) * 8;
        const int cpg = (g < 8) ? 9 : 8;
        const int wave = tid >> 6, lane = tid & 63;

        float* cur = (float*)P;           // 36 KB buffers
        float* nxt = (float*)U;

        int se[9];
        #pragma unroll
        for (int k = 0; k < 9; ++k) {
            int e = tid + k * 1024;
            se[k] = (e < E) ? tree[((size_t)b * E + e) * 2] : 0;
        }
        float acc[9];
        #pragma unroll
        for (int k = 0; k < 9; ++k) acc[k] = 0.f;

        // async stage of one 36 KB channel row: 36 chunks of 1 KB (64 lanes x 16 B)
        const float* rowbase = emb + ((size_t)b * C + c0) * N;
        for (int chk = wave; chk < 36; chk += 16)
            __builtin_amdgcn_global_load_lds(
                (GVoid*)(rowbase + chk * 256 + lane * 4),
                (LVoid*)(cur + chk * 256), 16, 0, 0);
        __syncthreads();                                 // ch0 ready

        for (int cc = 0; cc < cpg; ++cc) {
            if (cc + 1 < cpg) {                          // async prefetch next channel
                const float* src = rowbase + (size_t)(cc + 1) * N;
                for (int chk = wave; chk < 36; chk += 16)
                    __builtin_amdgcn_global_load_lds(
                        (GVoid*)(src + chk * 256 + lane * 4),
                        (LVoid*)(nxt + chk * 256), 16, 0, 0);
            }
            #pragma unroll
            for (int k = 0; k < 9; ++k) {
                int e = tid + k * 1024;
                if (e < E) {
                    float d = cur[se[k]] - cur[e + 1];   // tgt = e+1 (children=arange)
                    acc[k] += d * d;
                }
            }
            __syncthreads();                             // nxt staged + cur reads done
            float* t = cur; cur = nxt; nxt = t;
        }
        #pragma unroll
        for (int k = 0; k < 9; ++k) {
            int e = tid + k * 1024;
            if (e < E) atomicAdd(&distG[(size_t)b * N + e], acc[k]);
        }
        return;
    }

    // ---- levels role (unchanged, proven) ----
    const int b = blockIdx.x;
    const int* tb = tree + b * E * 2;

    for (int t = tid; t < N; t += 1024)
        P[t] = (t == 0) ? 0 : (tb[(t - 1) * 2] | (1 << 16));
    for (int i = tid; i < MAXD * 8; i += 1024) cnt8[i] = 0;
    if (tid == 0) maxd_sh = 1;
    __syncthreads();

    // packed pointer doubling P<->U with converged-node skip (depth <= 64)
    for (int r = 0; r < 3; ++r) {
        for (int t = tid; t < N; t += 1024) {
            int p = P[t];
            int a = p & 0xffff;
            if (a == 0) U[t] = p;
            else {
                int pa = P[a];
                U[t] = (pa & 0xffff) | (((p >> 16) + (pa >> 16)) << 16);
            }
        }
        __syncthreads();
        for (int t = tid; t < N; t += 1024) {
            int p = U[t];
            int a = p & 0xffff;
            if (a == 0) P[t] = p;
            else {
                int pa = U[a];
                P[t] = (pa & 0xffff) | (((p >> 16) + (pa >> 16)) << 16);
            }
        }
        __syncthreads();
    }

    // depth histogram into 8 sub-counters per level
    for (int t = 1 + tid; t < N; t += 1024) {
        int d = P[t] >> 16;
        atomicAdd(&cnt8[d * 8 + (tid >> 7)], 1);
    }
    __syncthreads();

    // sub-prefix within each level + totals
    for (int d = tid; d < MAXD; d += 1024) {
        int s = 0;
        #pragma unroll
        for (int k = 0; k < 8; ++k) {
            int v = cnt8[d * 8 + k];
            cnt8[d * 8 + k] = s;
            s += v;
        }
        tot[d] = s;
        if (s > 0) atomicMax(&maxd_sh, d);
    }
    __syncthreads();

    // Hillis-Steele inclusive scan over level totals -> off
    {
        int* src = tot; int* dst = sc1;
        for (int step = 1; step < MAXD; step <<= 1) {
            for (int d = tid; d < MAXD; d += 1024)
                dst[d] = src[d] + ((d >= step) ? src[d - step] : 0);
            __syncthreads();
            int* tmp = src; src = dst; dst = tmp;
        }
        for (int d = tid; d < MAXD; d += 1024) off[d + 1] = src[d];
        if (tid == 0) off[0] = 0;
    }
    __syncthreads();

    // narrow/wide markers + counting-sort scatter into LDS
    if (tid == 0) {
        int md = maxd_sh;
        int lo = 0;
        while (lo < md && off[lo + 2] - off[lo + 1] <= NARROW) ++lo;
        int hi = md + 1;
        while (hi > lo + 1 && off[hi] - off[hi - 1] <= NARROW) --hi;
        lvlOff[b * LVL_STRIDE + 129] = md;
        lvlOff[b * LVL_STRIDE + 130] = lo;
        lvlOff[b * LVL_STRIDE + 131] = hi;
    }
    for (int t = 1 + tid; t < N; t += 1024) {
        int d = P[t] >> 16;
        int idx = atomicAdd(&cnt8[d * 8 + (tid >> 7)], 1);
        int slot = off[d] + idx;
        int p = tb[(t - 1) * 2];          // L2-hot re-read
        U[slot] = t | (p << 16);
    }
    __syncthreads();

    // coalesced flush
    for (int i = tid; i < E; i += 1024) uparr[b * N + i] = U[i];
    for (int i = tid; i <= MAXD; i += 1024) lvlOff[b * LVL_STRIDE + i] = off[i];
}

// ---------------------------------------------------------------------------
// Kernel 2: LDS-resident tree DP (unchanged, proven 47.4 us).
// ---------------------------------------------------------------------------
__device__ __forceinline__ void up_edge(float2* V, const int2& ew) {
    int t = ew.x & 0xffff, p = ew.x >> 16;
    float w = __int_as_float(ew.y);
    float2 vt = V[t];
    atomicAdd(&V[p].x, w * vt.x);
    atomicAdd(&V[p].y, w * vt.y);
}

__device__ __forceinline__ void down_edge(float2* V, const int2& ew) {
    int t = ew.x & 0xffff, s = ew.x >> 16;
    float w = __int_as_float(ew.y);
    float2 vs = V[s], vt = V[t];
    float c = 1.f - w * w;
    V[t] = make_float2(w * vs.x + c * vt.x, w * vs.y + c * vt.y);
}

__global__ __launch_bounds__(512) void dp_kernel(const float* __restrict__ feat,
                                                 const int* __restrict__ lvlOff,
                                                 const int* __restrict__ uparr,
                                                 const float* __restrict__ distG,
                                                 float* __restrict__ out) {
    const int b = blockIdx.x;
    const int tid = threadIdx.x;
    __shared__ float2 V[N];           // (F, G)
    __shared__ int2 TSW[N];           // (child|parent<<16, w bits), level order
    __shared__ int off[MAXD + 1];
    __shared__ int meta[3];           // maxd, loE, hiS

    for (int i = tid; i <= MAXD; i += 512) off[i] = lvlOff[b * LVL_STRIDE + i];
    if (tid < 3) meta[tid] = lvlOff[b * LVL_STRIDE + 129 + tid];

    const int* uA = uparr + b * N;
    const float* dG = distG + b * N;
    for (int i = tid; i < N; i += 512)
        V[i] = make_float2(feat[b * N + i], 1.0f);
    for (int i = tid; i < E; i += 512) {             // coalesced ts + pipelined gather
        int ts = uA[i];
        float ds = dG[(ts & 0xffff) - 1];
        TSW[i] = make_int2(ts, __float_as_int(__expf(-0.01f * ds)));
    }
    __syncthreads();
    const int maxd = meta[0], loE = meta[1], hiS = meta[2];

    // ---- up pass (deepest level first) ----
    if (tid < 64) {                                  // narrow deep tail: wave 0
        for (int lev = maxd; lev >= hiS; --lev) {
            int s0 = off[lev], s1 = off[lev + 1];
            for (int i = s0 + tid; i < s1; i += 64) up_edge(V, TSW[i]);
            __threadfence_block();
        }
    }
    __syncthreads();
    for (int lev = hiS - 1; lev > loE; --lev) {      // wide middle: all waves
        int s0 = off[lev], s1 = off[lev + 1];
        for (int i = s0 + tid; i < s1; i += 512) up_edge(V, TSW[i]);
        __syncthreads();
    }
    if (tid < 64) {                                  // narrow top: wave 0
        for (int lev = loE; lev >= 1; --lev) {
            int s0 = off[lev], s1 = off[lev + 1];
            for (int i = s0 + tid; i < s1; i += 64) up_edge(V, TSW[i]);
            __threadfence_block();
        }
    }
    __syncthreads();

    // ---- down pass (root to leaf) ----
    if (tid < 64) {                                  // narrow top: wave 0
        for (int lev = 1; lev <= loE; ++lev) {
            int s0 = off[lev], s1 = off[lev + 1];
            for (int i = s0 + tid; i < s1; i += 64) down_edge(V, TSW[i]);
            __threadfence_block();
        }
    }
    __syncthreads();
    for (int lev = loE + 1; lev < hiS; ++lev) {      // wide middle: all waves
        int s0 = off[lev], s1 = off[lev + 1];
        for (int i = s0 + tid; i < s1; i += 512) down_edge(V, TSW[i]);
        __syncthreads();
    }
    if (tid < 64) {                                  // narrow deep tail: wave 0
        for (int lev = hiS; lev <= maxd; ++lev) {
            int s0 = off[lev], s1 = off[lev + 1];
            for (int i = s0 + tid; i < s1; i += 64) down_edge(V, TSW[i]);
            __threadfence_block();
        }
    }
    __syncthreads();

    for (int i = tid; i < N; i += 512) {
        float2 v = V[i];
        out[b * N + i] = v.x / v.y;
    }
}

extern "C" void kernel_launch(void* const* d_in, const int* in_sizes, int n_in,
                              void* d_out, int out_size, void* d_ws, size_t ws_size,
                              hipStream_t stream) {
    const float* feat = (const float*)d_in[0];   // [8,1,96,96]
    const float* emb  = (const float*)d_in[1];   // [8,256,96,96]
    const int*   tree = (const int*)d_in[2];     // [8,9215,2]
    float* out = (float*)d_out;                  // [8,1,96,96]

    const size_t BN = (size_t)BS * N;
    float* distG  = (float*)d_ws;                            // BN f32 (edge-indexed sq-dist)
    int*   uparr  = (int*)((char*)d_ws + BN * 4);            // BN i32 (level order)
    int*   lvlOff = (int*)((char*)d_ws + BN * 8);            // BS*LVL_STRIDE i32

    hipMemsetAsync(distG, 0, BN * sizeof(float), stream);    // capture-legal
    setup_kernel<<<NBLK, 1024, 0, stream>>>(emb, tree, distG, uparr, lvlOff);
    dp_kernel<<<BS, 512, 0, stream>>>(feat, lvlOff, uparr, distG, out);
}